// Round 5
// baseline (352.561 us; speedup 1.0000x reference)
//
#include <hip/hip_runtime.h>
#include <hip/hip_bf16.h>

typedef unsigned short u16;
typedef unsigned int u32;

#define NN 100000
#define NE 3200000
#define NF 128
#define DM 32
#define NGR 1024
#define NCL 10

#define GEMM_BLOCKS (NN / 32)          // 3125
#define BW 256                         // nodes per bucket (dst >> 8)
#define BK 391                         // ceil(NN / BW)
#define NEB 8192                       // edges per bin block
#define NB 391                         // bin blocks = ceil(NE / NEB)
#define SHALF 50000                    // src-half split: table half = 3.2MB, fits 4MB XCD L2
#define LSLOT 9216                     // LDS slot staging (mean 8192 + 11 sigma)

__device__ __forceinline__ float blo(u32 u) { return __uint_as_float(u << 16); }
__device__ __forceinline__ float bhi(u32 u) { return __uint_as_float(u & 0xffff0000u); }
__device__ __forceinline__ u16 f2b(float f) {
  __hip_bfloat16 h = __float2bfloat16(f);
  return *reinterpret_cast<u16*>(&h);
}

// ---------------------------------------------------------------------------
// 32x32 GEMM from LDS: out[j] = sum_k src[(ng*4+j)*32+k] * w[k*32+d]
__device__ __forceinline__ void gemm32(const float* __restrict__ s, const float* __restrict__ w,
                                       int d, int ng, float acc[4]) {
  const float4* r0 = reinterpret_cast<const float4*>(s + (ng * 4 + 0) * DM);
  const float4* r1 = reinterpret_cast<const float4*>(s + (ng * 4 + 1) * DM);
  const float4* r2 = reinterpret_cast<const float4*>(s + (ng * 4 + 2) * DM);
  const float4* r3 = reinterpret_cast<const float4*>(s + (ng * 4 + 3) * DM);
  float a0 = 0.f, a1 = 0.f, a2 = 0.f, a3 = 0.f;
#pragma unroll
  for (int kk = 0; kk < 8; ++kk) {
    float4 x0 = r0[kk], x1 = r1[kk], x2 = r2[kk], x3 = r3[kk];
    float w0 = w[(kk * 4 + 0) * DM + d];
    float w1 = w[(kk * 4 + 1) * DM + d];
    float w2 = w[(kk * 4 + 2) * DM + d];
    float w3 = w[(kk * 4 + 3) * DM + d];
    a0 = fmaf(x0.x, w0, a0); a0 = fmaf(x0.y, w1, a0); a0 = fmaf(x0.z, w2, a0); a0 = fmaf(x0.w, w3, a0);
    a1 = fmaf(x1.x, w0, a1); a1 = fmaf(x1.y, w1, a1); a1 = fmaf(x1.z, w2, a1); a1 = fmaf(x1.w, w3, a1);
    a2 = fmaf(x2.x, w0, a2); a2 = fmaf(x2.y, w1, a2); a2 = fmaf(x2.z, w2, a2); a2 = fmaf(x2.w, w3, a2);
    a3 = fmaf(x3.x, w0, a3); a3 = fmaf(x3.y, w1, a3); a3 = fmaf(x3.z, w2, a3); a3 = fmaf(x3.w, w3, a3);
  }
  acc[0] = a0; acc[1] = a1; acc[2] = a2; acc[3] = a3;
}

// Per-node CSR gather from a bf16 table (rows of 32 bf16 = 64B). 8 lanes per
// node, lane c loads uint2 (4 bf16) per neighbor; 16/8-deep bursts.
__device__ __forceinline__ float4 gather16b(const uint2* __restrict__ y2v,
                                            const int* __restrict__ slot,
                                            int beg, int end, int c) {
  float ax = 0.f, ay = 0.f, az = 0.f, aw = 0.f;
  int i = beg;
  for (; i + 16 <= end; i += 16) {
    int sl[16];
#pragma unroll
    for (int j = 0; j < 16; ++j) sl[j] = slot[i + j];
    uint2 vv[16];
#pragma unroll
    for (int j = 0; j < 16; ++j) vv[j] = y2v[(size_t)sl[j] * 8 + c];
#pragma unroll
    for (int j = 0; j < 16; ++j) {
      ax += blo(vv[j].x); ay += bhi(vv[j].x); az += blo(vv[j].y); aw += bhi(vv[j].y);
    }
  }
  if (i + 8 <= end) {
    int sl[8];
#pragma unroll
    for (int j = 0; j < 8; ++j) sl[j] = slot[i + j];
    uint2 vv[8];
#pragma unroll
    for (int j = 0; j < 8; ++j) vv[j] = y2v[(size_t)sl[j] * 8 + c];
#pragma unroll
    for (int j = 0; j < 8; ++j) {
      ax += blo(vv[j].x); ay += bhi(vv[j].x); az += blo(vv[j].y); aw += bhi(vv[j].y);
    }
    i += 8;
  }
  for (; i < end; ++i) {
    int s = slot[i];
    uint2 v = y2v[(size_t)s * 8 + c];
    ax += blo(v.x); ay += bhi(v.x); az += blo(v.y); aw += bhi(v.y);
  }
  return make_float4(ax, ay, az, aw);
}

// ---------------------------------------------------------------------------
// Per-binblock bucket histogram -> hmat[b][k] (coalesced row write).
__global__ __launch_bounds__(256) void k_bhist2(const int* __restrict__ ei,
                                                int* __restrict__ hmat) {
  __shared__ int h[BK];
  const int t = threadIdx.x, b = blockIdx.x;
  for (int i = t; i < BK; i += 256) h[i] = 0;
  __syncthreads();
  const int e0 = b * NEB;
#pragma unroll
  for (int k = 0; k < NEB / 256; ++k) {
    int e = e0 + k * 256 + t;
    if (e < NE) atomicAdd(&h[ei[NE + e] >> 8], 1);
  }
  __syncthreads();
  for (int i = t; i < BK; i += 256) hmat[(size_t)b * BK + i] = h[i];
}

// Column-k exclusive scan of hmat -> offT[k][b]; column total -> colsum[k].
__global__ __launch_bounds__(256) void k_bscan2(const int* __restrict__ hmat,
                                                int* __restrict__ offT,
                                                int* __restrict__ colsum) {
  __shared__ int v[NB];
  __shared__ int ts[256];
  const int t = threadIdx.x, k = blockIdx.x;
  for (int i = t; i < NB; i += 256) v[i] = hmat[(size_t)i * BK + k];
  __syncthreads();
  int loc[2]; int s = 0;
#pragma unroll
  for (int j = 0; j < 2; ++j) {
    int idx = t * 2 + j;
    loc[j] = (idx < NB) ? v[idx] : 0;
    s += loc[j];
  }
  ts[t] = s;
  __syncthreads();
  for (int off = 1; off < 256; off <<= 1) {
    int x = (t >= off) ? ts[t - off] : 0;
    __syncthreads();
    ts[t] += x;
    __syncthreads();
  }
  int run = ts[t] - s;   // exclusive across threads
#pragma unroll
  for (int j = 0; j < 2; ++j) {
    int idx = t * 2 + j;
    if (idx < NB) offT[(size_t)k * NB + idx] = run;
    run += loc[j];
  }
  if (t == 255) colsum[k] = run;
}

// Scan colsum -> cbase; rowptr[NN]=NE; zero pool (replaces memset dispatch).
__global__ __launch_bounds__(512) void k_bscan3(const int* __restrict__ colsum,
                                                int* __restrict__ cbase,
                                                int* __restrict__ rowptr,
                                                float* __restrict__ pool) {
  __shared__ int ps[512];
  const int t = threadIdx.x;
  int own = (t < BK) ? colsum[t] : 0;
  ps[t] = own;
  __syncthreads();
  for (int off = 1; off < 512; off <<= 1) {
    int x = (t >= off) ? ps[t - off] : 0;
    __syncthreads();
    ps[t] += x;
    __syncthreads();
  }
  if (t < BK) cbase[t] = ps[t] - own;
  if (t == 0) { cbase[BK] = NE; rowptr[NN] = NE; }
  float4 z = {0.f, 0.f, 0.f, 0.f};
  float4* p4 = reinterpret_cast<float4*>(pool);
  for (int i = t; i < NGR * DM / 4; i += 512) p4[i] = z;
}

// ---------------------------------------------------------------------------
// Fused dispatch: blocks [0, NB) bin edges (FIRST so all bin blocks are
// co-resident from t=0); blocks [NB, ..) do y1 = x @ w1a.
__global__ __launch_bounds__(256) void k_gemm_bin(
    const float* __restrict__ x, const float* __restrict__ w, u16* __restrict__ y,
    const int* __restrict__ ei, const int* __restrict__ cbase,
    const int* __restrict__ offT, int* __restrict__ binned) {
  __shared__ alignas(16) char smem[32768];
  const int t = threadIdx.x;
  if (blockIdx.x < NB) {
    int* lofs = (int*)smem;           // [BK]
    int* lcur = lofs + BK;            // [BK]
    const int bb = blockIdx.x;
    for (int i = t; i < BK; i += 256) {
      lofs[i] = cbase[i] + offT[(size_t)i * NB + bb];
      lcur[i] = 0;
    }
    __syncthreads();
    const int e0 = bb * NEB;
#pragma unroll
    for (int k = 0; k < NEB / 256; ++k) {
      int e = e0 + k * 256 + t;
      if (e < NE) {
        int s = ei[e], d = ei[NE + e];
        int bk = d >> 8;
        int l = atomicAdd(&lcur[bk], 1);
        binned[lofs[bk] + l] = (s << 8) | (d & 255);
      }
    }
    return;
  }
  // ---- in_gemm: y1 = x @ w1a (bf16 store) ----
  float* wl = (float*)smem;           // 16KB
  float* xl = wl + NF * DM;           // 16KB
  const int n0 = (blockIdx.x - NB) * 32;
  {
    const float4* wv = reinterpret_cast<const float4*>(w);
    float4* wld = reinterpret_cast<float4*>(wl);
    for (int i = t; i < NF * DM / 4; i += 256) wld[i] = wv[i];
    const float4* xv = reinterpret_cast<const float4*>(x + (size_t)n0 * NF);
    float4* xld = reinterpret_cast<float4*>(xl);
    for (int i = t; i < 32 * NF / 4; i += 256) xld[i] = xv[i];
  }
  __syncthreads();
  const int d = t & 31, ng = t >> 5;
  const float4* r0 = reinterpret_cast<const float4*>(&xl[(ng * 4 + 0) * NF]);
  const float4* r1 = reinterpret_cast<const float4*>(&xl[(ng * 4 + 1) * NF]);
  const float4* r2 = reinterpret_cast<const float4*>(&xl[(ng * 4 + 2) * NF]);
  const float4* r3 = reinterpret_cast<const float4*>(&xl[(ng * 4 + 3) * NF]);
  float a0 = 0.f, a1 = 0.f, a2 = 0.f, a3 = 0.f;
#pragma unroll 4
  for (int kk = 0; kk < NF / 4; ++kk) {
    float4 x0 = r0[kk], x1 = r1[kk], x2 = r2[kk], x3 = r3[kk];
    float w0 = wl[(kk * 4 + 0) * DM + d];
    float w1 = wl[(kk * 4 + 1) * DM + d];
    float w2 = wl[(kk * 4 + 2) * DM + d];
    float w3 = wl[(kk * 4 + 3) * DM + d];
    a0 = fmaf(x0.x, w0, a0); a0 = fmaf(x0.y, w1, a0); a0 = fmaf(x0.z, w2, a0); a0 = fmaf(x0.w, w3, a0);
    a1 = fmaf(x1.x, w0, a1); a1 = fmaf(x1.y, w1, a1); a1 = fmaf(x1.z, w2, a1); a1 = fmaf(x1.w, w3, a1);
    a2 = fmaf(x2.x, w0, a2); a2 = fmaf(x2.y, w1, a2); a2 = fmaf(x2.z, w2, a2); a2 = fmaf(x2.w, w3, a2);
    a3 = fmaf(x3.x, w0, a3); a3 = fmaf(x3.y, w1, a3); a3 = fmaf(x3.z, w2, a3); a3 = fmaf(x3.w, w3, a3);
  }
  u16* yo = y + (size_t)n0 * DM;
  yo[(ng * 4 + 0) * DM + d] = f2b(a0);
  yo[(ng * 4 + 1) * DM + d] = f2b(a1);
  yo[(ng * 4 + 2) * DM + d] = f2b(a2);
  yo[(ng * 4 + 3) * DM + d] = f2b(a3);
}

// ---------------------------------------------------------------------------
// Per-bucket CSR finalize (512 threads). Each node's list is two-segment
// ordered [src < SHALF][src >= SHALF]; rowmid marks the boundary so the conv
// kernels can gather the halves in separate dispatches (L2-resident table).
__global__ __launch_bounds__(512) void k_fill2(const int* __restrict__ binned,
                                               const int* __restrict__ cbase,
                                               int* __restrict__ rowptr,
                                               int* __restrict__ rowmid,
                                               int* __restrict__ slot) {
  __shared__ int deg[BW], degL[BW], curL[BW], curH[BW], ps[256];
  __shared__ int lslot[LSLOT];
  const int t = threadIdx.x, b = blockIdx.x;
  const int n0 = b * BW;
  const int e0 = cbase[b], e1 = cbase[b + 1];
  const int cnt = e1 - e0;
  if (t < BW) { deg[t] = 0; degL[t] = 0; }
  __syncthreads();
  for (int j = e0 + t; j < e1; j += 512) {
    int v = binned[j];
    int dl = v & 255;
    atomicAdd(&deg[dl], 1);
    if ((((u32)v) >> 8) < SHALF) atomicAdd(&degL[dl], 1);
  }
  __syncthreads();
  int own = (t < 256) ? deg[t] : 0;
  if (t < 256) ps[t] = own;
  __syncthreads();
  for (int off = 1; off < 256; off <<= 1) {
    int v = (t < 256 && t >= off) ? ps[t - off] : 0;
    __syncthreads();
    if (t < 256) ps[t] += v;
    __syncthreads();
  }
  if (t < 256) {
    int ex = ps[t] - own;
    curL[t] = ex;
    curH[t] = ex + degL[t];
    if (n0 + t < NN) {
      rowptr[n0 + t] = e0 + ex;
      rowmid[n0 + t] = e0 + ex + degL[t];
    }
  }
  __syncthreads();
  if (cnt <= LSLOT) {
    for (int j = e0 + t; j < e1; j += 512) {
      int v = binned[j];
      u32 s = ((u32)v) >> 8;
      int dl = v & 255;
      int p = (s < SHALF) ? atomicAdd(&curL[dl], 1) : atomicAdd(&curH[dl], 1);
      lslot[p] = (int)s;
    }
    __syncthreads();
    for (int j = t; j < cnt; j += 512) slot[e0 + j] = lslot[j];
  } else {
    for (int j = e0 + t; j < e1; j += 512) {
      int v = binned[j];
      u32 s = ((u32)v) >> 8;
      int dl = v & 255;
      int p = (s < SHALF) ? atomicAdd(&curL[dl], 1) : atomicAdd(&curH[dl], 1);
      slot[e0 + p] = (int)s;
    }
  }
}

// ---------------------------------------------------------------------------
// Conv pass A: gather ONLY lo-half neighbors (table rows [0, SHALF) = 3.2MB,
// resident in each XCD's 4MB L2 for the whole dispatch) -> f32 partials.
__global__ __launch_bounds__(256) void k_conv_a(
    const u16* __restrict__ yin,
    const int* __restrict__ rowptr, const int* __restrict__ rowmid,
    const int* __restrict__ slot, float* __restrict__ paggr) {
  const int t = threadIdx.x;
  const int n = blockIdx.x * 32 + (t >> 3), c = t & 7;
  const uint2* y2v = reinterpret_cast<const uint2*>(yin);
  float4 av = gather16b(y2v, slot, rowptr[n], rowmid[n], c);
  reinterpret_cast<float4*>(paggr)[(size_t)n * 8 + c] = av;
}

// Conv1 pass B: gather hi-half (table rows [SHALF, NN) L2-resident), add
// partials, then t=relu(y+agg+b1a); h1=bn1(relu(t@w1b+b1b)); yout <- h1@w2a.
__global__ __launch_bounds__(256) void k_mid_b(
    const u16* __restrict__ yin, u16* __restrict__ yout,
    const int* __restrict__ rowptr, const int* __restrict__ rowmid,
    const int* __restrict__ slot, const float* __restrict__ paggr,
    const float* __restrict__ b1a, const float* __restrict__ w1b, const float* __restrict__ b1b,
    const float* __restrict__ bng, const float* __restrict__ bnb,
    const float* __restrict__ bnm, const float* __restrict__ bnv,
    const float* __restrict__ w2a) {
  __shared__ float tl[1024], hl[1024], w1[1024], w2[1024];
  const int t = threadIdx.x;
  const int n0 = blockIdx.x * 32;
  reinterpret_cast<float4*>(w1)[t] = reinterpret_cast<const float4*>(w1b)[t];
  reinterpret_cast<float4*>(w2)[t] = reinterpret_cast<const float4*>(w2a)[t];
  {
    const int n = n0 + (t >> 3), c = t & 7;
    const uint2* y2v = reinterpret_cast<const uint2*>(yin);
    float4 av = gather16b(y2v, slot, rowmid[n], rowptr[n + 1], c);
    float4 pv = reinterpret_cast<const float4*>(paggr)[(size_t)n * 8 + c];
    av.x += pv.x; av.y += pv.y; av.z += pv.z; av.w += pv.w;
    uint2 yv = y2v[(size_t)n0 * 8 + t];
    int b = t * 4;
    tl[b + 0] = fmaxf(blo(yv.x) + av.x + b1a[(b + 0) & 31], 0.f);
    tl[b + 1] = fmaxf(bhi(yv.x) + av.y + b1a[(b + 1) & 31], 0.f);
    tl[b + 2] = fmaxf(blo(yv.y) + av.z + b1a[(b + 2) & 31], 0.f);
    tl[b + 3] = fmaxf(bhi(yv.y) + av.w + b1a[(b + 3) & 31], 0.f);
  }
  __syncthreads();
  const int d = t & 31, ng = t >> 5;
  float acc[4];
  gemm32(tl, w1, d, ng, acc);
  float bias2 = b1b[d];
  float sc = bng[d] / sqrtf(bnv[d] + 1e-5f);
  float sh = bnb[d] - bnm[d] * sc;
#pragma unroll
  for (int j = 0; j < 4; ++j)
    hl[(ng * 4 + j) * DM + d] = fmaxf(acc[j] + bias2, 0.f) * sc + sh;
  __syncthreads();
  gemm32(hl, w2, d, ng, acc);
  u16* yo = yout + (size_t)n0 * DM;
#pragma unroll
  for (int j = 0; j < 4; ++j)
    yo[(ng * 4 + j) * DM + d] = f2b(acc[j]);
}

// Conv2 pass B + head: gather hi-half of y2, add partials; conv2 MLP + bn2 +
// fc1 + fc2 + pool.
__global__ __launch_bounds__(256) void k_tail_b(
    const u16* __restrict__ y,
    const int* __restrict__ rowptr, const int* __restrict__ rowmid,
    const int* __restrict__ slot, const float* __restrict__ paggr,
    const int* __restrict__ batch,
    const float* __restrict__ b2a, const float* __restrict__ w2b, const float* __restrict__ b2b,
    const float* __restrict__ bng, const float* __restrict__ bnb,
    const float* __restrict__ bnm, const float* __restrict__ bnv,
    const float* __restrict__ fc1w, const float* __restrict__ fc1b,
    const float* __restrict__ fc2w, const float* __restrict__ fc2b,
    float* __restrict__ pool) {
  __shared__ float tl[1024], hl[1024], wA[1024], wB[1024], wC[1024];
  const int t = threadIdx.x;
  const int n0 = blockIdx.x * 32;
  reinterpret_cast<float4*>(wA)[t] = reinterpret_cast<const float4*>(w2b)[t];
  reinterpret_cast<float4*>(wB)[t] = reinterpret_cast<const float4*>(fc1w)[t];
  reinterpret_cast<float4*>(wC)[t] = reinterpret_cast<const float4*>(fc2w)[t];
  {
    const int n = n0 + (t >> 3), c = t & 7;
    const uint2* y2v = reinterpret_cast<const uint2*>(y);
    float4 av = gather16b(y2v, slot, rowmid[n], rowptr[n + 1], c);
    float4 pv = reinterpret_cast<const float4*>(paggr)[(size_t)n * 8 + c];
    av.x += pv.x; av.y += pv.y; av.z += pv.z; av.w += pv.w;
    uint2 yv = y2v[(size_t)n0 * 8 + t];
    int b = t * 4;
    tl[b + 0] = fmaxf(blo(yv.x) + av.x + b2a[(b + 0) & 31], 0.f);
    tl[b + 1] = fmaxf(bhi(yv.x) + av.y + b2a[(b + 1) & 31], 0.f);
    tl[b + 2] = fmaxf(blo(yv.y) + av.z + b2a[(b + 2) & 31], 0.f);
    tl[b + 3] = fmaxf(bhi(yv.y) + av.w + b2a[(b + 3) & 31], 0.f);
  }
  __syncthreads();
  const int d = t & 31, ng = t >> 5;
  float acc[4];
  gemm32(tl, wA, d, ng, acc);
  {
    float bias2 = b2b[d];
    float sc = bng[d] / sqrtf(bnv[d] + 1e-5f);
    float sh = bnb[d] - bnm[d] * sc;
#pragma unroll
    for (int j = 0; j < 4; ++j)
      hl[(ng * 4 + j) * DM + d] = fmaxf(acc[j] + bias2, 0.f) * sc + sh;
  }
  __syncthreads();
  gemm32(hl, wB, d, ng, acc);
  {
    float b1 = fc1b[d];
#pragma unroll
    for (int j = 0; j < 4; ++j)
      tl[(ng * 4 + j) * DM + d] = fmaxf(acc[j] + b1, 0.f);
  }
  __syncthreads();
  gemm32(tl, wC, d, ng, acc);
  float b2 = fc2b[d];
  float h0 = acc[0] + b2, h1 = acc[1] + b2, h2 = acc[2] + b2, h3 = acc[3] + b2;
  int nb = n0 + ng * 4;
  int g0 = batch[nb], g1 = batch[nb + 1], g2 = batch[nb + 2], g3 = batch[nb + 3];
  float s = h0; int gp = g0;
  if (g1 == gp) { s += h1; } else { atomicAdd(&pool[gp * DM + d], s); gp = g1; s = h1; }
  if (g2 == gp) { s += h2; } else { atomicAdd(&pool[gp * DM + d], s); gp = g2; s = h2; }
  if (g3 == gp) { s += h3; } else { atomicAdd(&pool[gp * DM + d], s); gp = g3; s = h3; }
  atomicAdd(&pool[gp * DM + d], s);
}

// out[g,c] = (pool[g,:]/max(cnt,1)) @ lin_w + lin_b ; counts via binary search.
__global__ __launch_bounds__(256) void k_out(
    const float* __restrict__ pool, const int* __restrict__ batch,
    const float* __restrict__ lw, const float* __restrict__ lb,
    float* __restrict__ out) {
  int tid = blockIdx.x * 256 + threadIdx.x;
  int g = tid >> 4, c = tid & 15;
  if (g >= NGR || c >= NCL) return;
  auto lower = [&](int key) {
    int lo = 0, hi = NN;
    while (lo < hi) { int mid = (lo + hi) >> 1; if (batch[mid] < key) lo = mid + 1; else hi = mid; }
    return lo;
  };
  int lo = lower(g), hi = lower(g + 1);
  float inv = 1.f / fmaxf((float)(hi - lo), 1.f);
  float acc = 0.f;
#pragma unroll
  for (int dd = 0; dd < DM; ++dd) acc = fmaf(pool[g * DM + dd], lw[dd * NCL + c], acc);
  out[g * NCL + c] = acc * inv + lb[c];
}

extern "C" void kernel_launch(void* const* d_in, const int* in_sizes, int n_in,
                              void* d_out, int out_size, void* d_ws, size_t ws_size,
                              hipStream_t stream) {
  const float* x   = (const float*)d_in[0];
  const int* ei    = (const int*)d_in[1];
  const int* batch = (const int*)d_in[2];
  const float* w1a = (const float*)d_in[3];  const float* b1a = (const float*)d_in[4];
  const float* w1b = (const float*)d_in[5];  const float* b1b = (const float*)d_in[6];
  const float* bn1g = (const float*)d_in[7]; const float* bn1b = (const float*)d_in[8];
  const float* bn1m = (const float*)d_in[9]; const float* bn1v = (const float*)d_in[10];
  const float* w2a = (const float*)d_in[11]; const float* b2a = (const float*)d_in[12];
  const float* w2b = (const float*)d_in[13]; const float* b2b = (const float*)d_in[14];
  const float* bn2g = (const float*)d_in[15]; const float* bn2b = (const float*)d_in[16];
  const float* bn2m = (const float*)d_in[17]; const float* bn2v = (const float*)d_in[18];
  const float* fc1w = (const float*)d_in[19]; const float* fc1b = (const float*)d_in[20];
  const float* fc2w = (const float*)d_in[21]; const float* fc2b = (const float*)d_in[22];
  const float* linw = (const float*)d_in[23]; const float* linb = (const float*)d_in[24];
  float* out = (float*)d_out;

  // workspace layout (~42 MB) — paggr aliases binned (dead after fill2);
  // rowmid aliases hmat (dead after bscan2).
  char* ws = (char*)d_ws;
  const size_t SZB = (size_t)NN * DM * 2;          // 6.4 MB (bf16 table)
  const size_t SZE = (size_t)NE * 4;               // 12.8 MB
  const size_t SZH = (size_t)NB * BK * 4;          // 612 KB
  u16* y1     = (u16*)(ws);
  u16* y2     = (u16*)(ws + SZB);
  int* slot   = (int*)(ws + 2 * SZB);
  int* binned = (int*)(ws + 2 * SZB + SZE);
  float* paggr = (float*)binned;                   // alias: NN*32*4 = 12.8MB
  int* hmat   = (int*)(ws + 2 * SZB + 2 * SZE);    // [NB][BK]
  int* rowmid = hmat;                              // alias: (NN)*4 <= 612KB? no: 400KB OK
  int* offT   = (int*)(ws + 2 * SZB + 2 * SZE + SZH); // [BK][NB]
  int* rowptr = (int*)(ws + 2 * SZB + 2 * SZE + 2 * SZH); // NN+1
  int* colsum = rowptr + (NN + 32);                // BK
  int* cbase  = colsum + 512;                      // BK+1
  float* pool = (float*)(cbase + 512);             // 128 KB

  // CSR build via bucket binning — zero global atomics (exact counting sort)
  k_bhist2<<<NB, 256, 0, stream>>>(ei, hmat);
  k_bscan2<<<BK, 256, 0, stream>>>(hmat, offT, colsum);
  k_bscan3<<<1, 512, 0, stream>>>(colsum, cbase, rowptr, pool);
  // fused: edge binning (bin blocks FIRST, co-resident)  ||  y1 = x@w1a (bf16)
  k_gemm_bin<<<NB + GEMM_BLOCKS, 256, 0, stream>>>(x, w1a, y1, ei, cbase, offT, binned);
  k_fill2<<<BK, 512, 0, stream>>>(binned, cbase, rowptr, rowmid, slot);

  // conv1: lo-half gather (L2-resident) -> partials; hi-half gather + MLP
  k_conv_a<<<NN / 32, 256, 0, stream>>>(y1, rowptr, rowmid, slot, paggr);
  k_mid_b<<<NN / 32, 256, 0, stream>>>(y1, y2, rowptr, rowmid, slot, paggr,
                                       b1a, w1b, b1b, bn1g, bn1b, bn1m, bn1v, w2a);
  // conv2: same two-phase split on y2
  k_conv_a<<<NN / 32, 256, 0, stream>>>(y2, rowptr, rowmid, slot, paggr);
  k_tail_b<<<NN / 32, 256, 0, stream>>>(y2, rowptr, rowmid, slot, paggr, batch,
                                        b2a, w2b, b2b, bn2g, bn2b, bn2m, bn2v,
                                        fc1w, fc1b, fc2w, fc2b, pool);
  k_out<<<(NGR * 16) / 256, 256, 0, stream>>>(pool, batch, linw, linb, out);
}

// Round 6
// 324.329 us; speedup vs baseline: 1.0870x; 1.0870x over previous
//
#include <hip/hip_runtime.h>
#include <hip/hip_bf16.h>

typedef unsigned short u16;
typedef unsigned int u32;

#define NN 100000
#define NE 3200000
#define NF 128
#define DM 32
#define NGR 1024
#define NCL 10

#define GEMM_BLOCKS (NN / 32)          // 3125
#define BW 256                         // nodes per bucket (dst >> 8)
#define BK 391                         // ceil(NN / BW)
#define NEB 8192                       // edges per bin block
#define NB 391                         // bin blocks = ceil(NE / NEB)
#define LSLOT 9216                     // LDS slot staging (mean 8192 + 11 sigma)

__device__ __forceinline__ float blo(u32 u) { return __uint_as_float(u << 16); }
__device__ __forceinline__ float bhi(u32 u) { return __uint_as_float(u & 0xffff0000u); }
__device__ __forceinline__ u16 f2b(float f) {
  __hip_bfloat16 h = __float2bfloat16(f);
  return *reinterpret_cast<u16*>(&h);
}

// ---------------------------------------------------------------------------
// 32x32 GEMM from LDS: out[j] = sum_k src[(ng*4+j)*32+k] * w[k*32+d]
__device__ __forceinline__ void gemm32(const float* __restrict__ s, const float* __restrict__ w,
                                       int d, int ng, float acc[4]) {
  const float4* r0 = reinterpret_cast<const float4*>(s + (ng * 4 + 0) * DM);
  const float4* r1 = reinterpret_cast<const float4*>(s + (ng * 4 + 1) * DM);
  const float4* r2 = reinterpret_cast<const float4*>(s + (ng * 4 + 2) * DM);
  const float4* r3 = reinterpret_cast<const float4*>(s + (ng * 4 + 3) * DM);
  float a0 = 0.f, a1 = 0.f, a2 = 0.f, a3 = 0.f;
#pragma unroll
  for (int kk = 0; kk < 8; ++kk) {
    float4 x0 = r0[kk], x1 = r1[kk], x2 = r2[kk], x3 = r3[kk];
    float w0 = w[(kk * 4 + 0) * DM + d];
    float w1 = w[(kk * 4 + 1) * DM + d];
    float w2 = w[(kk * 4 + 2) * DM + d];
    float w3 = w[(kk * 4 + 3) * DM + d];
    a0 = fmaf(x0.x, w0, a0); a0 = fmaf(x0.y, w1, a0); a0 = fmaf(x0.z, w2, a0); a0 = fmaf(x0.w, w3, a0);
    a1 = fmaf(x1.x, w0, a1); a1 = fmaf(x1.y, w1, a1); a1 = fmaf(x1.z, w2, a1); a1 = fmaf(x1.w, w3, a1);
    a2 = fmaf(x2.x, w0, a2); a2 = fmaf(x2.y, w1, a2); a2 = fmaf(x2.z, w2, a2); a2 = fmaf(x2.w, w3, a2);
    a3 = fmaf(x3.x, w0, a3); a3 = fmaf(x3.y, w1, a3); a3 = fmaf(x3.z, w2, a3); a3 = fmaf(x3.w, w3, a3);
  }
  acc[0] = a0; acc[1] = a1; acc[2] = a2; acc[3] = a3;
}

// Per-node CSR gather from a bf16 table (rows of 32 bf16 = 64B). 8 lanes per
// node, lane c loads uint2 (4 bf16) per neighbor. sched_barrier(0) fences pin
// all 16 row loads in flight BEFORE any consumption (compiler otherwise splits
// to 2x8 — r4 showed VGPR stuck at 56, i.e. the deep burst never materialized).
__device__ __forceinline__ float4 gather16f(const uint2* __restrict__ y2v,
                                            const int* __restrict__ slot,
                                            int beg, int end, int c) {
  float ax = 0.f, ay = 0.f, az = 0.f, aw = 0.f;
  int i = beg;
  for (; i + 16 <= end; i += 16) {
    int sl[16];
#pragma unroll
    for (int j = 0; j < 16; ++j) sl[j] = slot[i + j];
    __builtin_amdgcn_sched_barrier(0);
    uint2 vv[16];
#pragma unroll
    for (int j = 0; j < 16; ++j) vv[j] = y2v[(size_t)sl[j] * 8 + c];
    __builtin_amdgcn_sched_barrier(0);
#pragma unroll
    for (int j = 0; j < 16; ++j) {
      ax += blo(vv[j].x); ay += bhi(vv[j].x); az += blo(vv[j].y); aw += bhi(vv[j].y);
    }
  }
  if (i + 8 <= end) {
    int sl[8];
#pragma unroll
    for (int j = 0; j < 8; ++j) sl[j] = slot[i + j];
    __builtin_amdgcn_sched_barrier(0);
    uint2 vv[8];
#pragma unroll
    for (int j = 0; j < 8; ++j) vv[j] = y2v[(size_t)sl[j] * 8 + c];
    __builtin_amdgcn_sched_barrier(0);
#pragma unroll
    for (int j = 0; j < 8; ++j) {
      ax += blo(vv[j].x); ay += bhi(vv[j].x); az += blo(vv[j].y); aw += bhi(vv[j].y);
    }
    i += 8;
  }
  for (; i < end; ++i) {
    int s = slot[i];
    uint2 v = y2v[(size_t)s * 8 + c];
    ax += blo(v.x); ay += bhi(v.x); az += blo(v.y); aw += bhi(v.y);
  }
  return make_float4(ax, ay, az, aw);
}

// ---------------------------------------------------------------------------
// Per-binblock bucket histogram -> hmat[b][k] (coalesced row write).
__global__ __launch_bounds__(256) void k_bhist2(const int* __restrict__ ei,
                                                int* __restrict__ hmat) {
  __shared__ int h[BK];
  const int t = threadIdx.x, b = blockIdx.x;
  for (int i = t; i < BK; i += 256) h[i] = 0;
  __syncthreads();
  const int e0 = b * NEB;
#pragma unroll
  for (int k = 0; k < NEB / 256; ++k) {
    int e = e0 + k * 256 + t;
    if (e < NE) atomicAdd(&h[ei[NE + e] >> 8], 1);
  }
  __syncthreads();
  for (int i = t; i < BK; i += 256) hmat[(size_t)b * BK + i] = h[i];
}

// Column-k exclusive scan of hmat -> offT[k][b]; column total -> colsum[k].
__global__ __launch_bounds__(256) void k_bscan2(const int* __restrict__ hmat,
                                                int* __restrict__ offT,
                                                int* __restrict__ colsum) {
  __shared__ int v[NB];
  __shared__ int ts[256];
  const int t = threadIdx.x, k = blockIdx.x;
  for (int i = t; i < NB; i += 256) v[i] = hmat[(size_t)i * BK + k];
  __syncthreads();
  int loc[2]; int s = 0;
#pragma unroll
  for (int j = 0; j < 2; ++j) {
    int idx = t * 2 + j;
    loc[j] = (idx < NB) ? v[idx] : 0;
    s += loc[j];
  }
  ts[t] = s;
  __syncthreads();
  for (int off = 1; off < 256; off <<= 1) {
    int x = (t >= off) ? ts[t - off] : 0;
    __syncthreads();
    ts[t] += x;
    __syncthreads();
  }
  int run = ts[t] - s;   // exclusive across threads
#pragma unroll
  for (int j = 0; j < 2; ++j) {
    int idx = t * 2 + j;
    if (idx < NB) offT[(size_t)k * NB + idx] = run;
    run += loc[j];
  }
  if (t == 255) colsum[k] = run;
}

// Scan colsum -> cbase; rowptr[NN]=NE; zero pool (replaces memset dispatch).
__global__ __launch_bounds__(512) void k_bscan3(const int* __restrict__ colsum,
                                                int* __restrict__ cbase,
                                                int* __restrict__ rowptr,
                                                float* __restrict__ pool) {
  __shared__ int ps[512];
  const int t = threadIdx.x;
  int own = (t < BK) ? colsum[t] : 0;
  ps[t] = own;
  __syncthreads();
  for (int off = 1; off < 512; off <<= 1) {
    int x = (t >= off) ? ps[t - off] : 0;
    __syncthreads();
    ps[t] += x;
    __syncthreads();
  }
  if (t < BK) cbase[t] = ps[t] - own;
  if (t == 0) { cbase[BK] = NE; rowptr[NN] = NE; }
  float4 z = {0.f, 0.f, 0.f, 0.f};
  float4* p4 = reinterpret_cast<float4*>(pool);
  for (int i = t; i < NGR * DM / 4; i += 512) p4[i] = z;
}

// ---------------------------------------------------------------------------
// Fused dispatch: blocks [0, NB) bin edges (FIRST so all bin blocks are
// co-resident from t=0 -> their adjacent chunks are written in one temporal
// window and merge into full sectors in L2); blocks [NB, ..) do y1 = x @ w1a.
__global__ __launch_bounds__(256) void k_gemm_bin(
    const float* __restrict__ x, const float* __restrict__ w, u16* __restrict__ y,
    const int* __restrict__ ei, const int* __restrict__ cbase,
    const int* __restrict__ offT, int* __restrict__ binned) {
  __shared__ alignas(16) char smem[32768];
  const int t = threadIdx.x;
  if (blockIdx.x < NB) {
    int* lofs = (int*)smem;           // [BK]
    int* lcur = lofs + BK;            // [BK]
    const int bb = blockIdx.x;
    for (int i = t; i < BK; i += 256) {
      lofs[i] = cbase[i] + offT[(size_t)i * NB + bb];
      lcur[i] = 0;
    }
    __syncthreads();
    const int e0 = bb * NEB;
#pragma unroll
    for (int k = 0; k < NEB / 256; ++k) {
      int e = e0 + k * 256 + t;
      if (e < NE) {
        int s = ei[e], d = ei[NE + e];
        int bk = d >> 8;
        int l = atomicAdd(&lcur[bk], 1);
        binned[lofs[bk] + l] = (s << 8) | (d & 255);
      }
    }
    return;
  }
  // ---- in_gemm: y1 = x @ w1a (bf16 store) ----
  float* wl = (float*)smem;           // 16KB
  float* xl = wl + NF * DM;           // 16KB
  const int n0 = (blockIdx.x - NB) * 32;
  {
    const float4* wv = reinterpret_cast<const float4*>(w);
    float4* wld = reinterpret_cast<float4*>(wl);
    for (int i = t; i < NF * DM / 4; i += 256) wld[i] = wv[i];
    const float4* xv = reinterpret_cast<const float4*>(x + (size_t)n0 * NF);
    float4* xld = reinterpret_cast<float4*>(xl);
    for (int i = t; i < 32 * NF / 4; i += 256) xld[i] = xv[i];
  }
  __syncthreads();
  const int d = t & 31, ng = t >> 5;
  const float4* r0 = reinterpret_cast<const float4*>(&xl[(ng * 4 + 0) * NF]);
  const float4* r1 = reinterpret_cast<const float4*>(&xl[(ng * 4 + 1) * NF]);
  const float4* r2 = reinterpret_cast<const float4*>(&xl[(ng * 4 + 2) * NF]);
  const float4* r3 = reinterpret_cast<const float4*>(&xl[(ng * 4 + 3) * NF]);
  float a0 = 0.f, a1 = 0.f, a2 = 0.f, a3 = 0.f;
#pragma unroll 4
  for (int kk = 0; kk < NF / 4; ++kk) {
    float4 x0 = r0[kk], x1 = r1[kk], x2 = r2[kk], x3 = r3[kk];
    float w0 = wl[(kk * 4 + 0) * DM + d];
    float w1 = wl[(kk * 4 + 1) * DM + d];
    float w2 = wl[(kk * 4 + 2) * DM + d];
    float w3 = wl[(kk * 4 + 3) * DM + d];
    a0 = fmaf(x0.x, w0, a0); a0 = fmaf(x0.y, w1, a0); a0 = fmaf(x0.z, w2, a0); a0 = fmaf(x0.w, w3, a0);
    a1 = fmaf(x1.x, w0, a1); a1 = fmaf(x1.y, w1, a1); a1 = fmaf(x1.z, w2, a1); a1 = fmaf(x1.w, w3, a1);
    a2 = fmaf(x2.x, w0, a2); a2 = fmaf(x2.y, w1, a2); a2 = fmaf(x2.z, w2, a2); a2 = fmaf(x2.w, w3, a2);
    a3 = fmaf(x3.x, w0, a3); a3 = fmaf(x3.y, w1, a3); a3 = fmaf(x3.z, w2, a3); a3 = fmaf(x3.w, w3, a3);
  }
  u16* yo = y + (size_t)n0 * DM;
  yo[(ng * 4 + 0) * DM + d] = f2b(a0);
  yo[(ng * 4 + 1) * DM + d] = f2b(a1);
  yo[(ng * 4 + 2) * DM + d] = f2b(a2);
  yo[(ng * 4 + 3) * DM + d] = f2b(a3);
}

// ---------------------------------------------------------------------------
// Per-bucket CSR finalize (512 threads): deg/scan/cursor and slot staging in
// LDS, coalesced stream-out. Fallback to direct writes on (improbable) overflow.
__global__ __launch_bounds__(512) void k_fill2(const int* __restrict__ binned,
                                               const int* __restrict__ cbase,
                                               int* __restrict__ rowptr,
                                               int* __restrict__ slot) {
  __shared__ int deg[BW], cur[BW], ps[256];
  __shared__ int lslot[LSLOT];
  const int t = threadIdx.x, b = blockIdx.x;
  const int n0 = b * BW;
  const int e0 = cbase[b], e1 = cbase[b + 1];
  const int cnt = e1 - e0;
  if (t < BW) deg[t] = 0;
  __syncthreads();
  for (int j = e0 + t; j < e1; j += 512) atomicAdd(&deg[binned[j] & 255], 1);
  __syncthreads();
  int own = (t < 256) ? deg[t] : 0;
  if (t < 256) ps[t] = own;
  __syncthreads();
  for (int off = 1; off < 256; off <<= 1) {
    int v = (t < 256 && t >= off) ? ps[t - off] : 0;
    __syncthreads();
    if (t < 256) ps[t] += v;
    __syncthreads();
  }
  if (t < 256) {
    int ex = ps[t] - own;
    cur[t] = ex;
    if (n0 + t < NN) rowptr[n0 + t] = e0 + ex;
  }
  __syncthreads();
  if (cnt <= LSLOT) {
    for (int j = e0 + t; j < e1; j += 512) {
      int v = binned[j];
      int p = atomicAdd(&cur[v & 255], 1);
      lslot[p] = (int)(((u32)v) >> 8);
    }
    __syncthreads();
    for (int j = t; j < cnt; j += 512) slot[e0 + j] = lslot[j];
  } else {
    for (int j = e0 + t; j < e1; j += 512) {
      int v = binned[j];
      int p = atomicAdd(&cur[v & 255], 1);
      slot[e0 + p] = (int)(((u32)v) >> 8);
    }
  }
}

// ---------------------------------------------------------------------------
// Fused conv1-tail: agg=gather(yin bf16); t=relu(yin+agg+b1a);
// h1=bn1(relu(t@w1b+b1b)); yout(bf16) <- h1@w2a.  yout != yin (gather race).
__global__ __launch_bounds__(256) void k_mid(
    const u16* __restrict__ yin, u16* __restrict__ yout,
    const int* __restrict__ rowptr, const int* __restrict__ slot,
    const float* __restrict__ b1a, const float* __restrict__ w1b, const float* __restrict__ b1b,
    const float* __restrict__ bng, const float* __restrict__ bnb,
    const float* __restrict__ bnm, const float* __restrict__ bnv,
    const float* __restrict__ w2a) {
  __shared__ float tl[1024], hl[1024], w1[1024], w2[1024];
  const int t = threadIdx.x;
  const int n0 = blockIdx.x * 32;
  reinterpret_cast<float4*>(w1)[t] = reinterpret_cast<const float4*>(w1b)[t];
  reinterpret_cast<float4*>(w2)[t] = reinterpret_cast<const float4*>(w2a)[t];
  {
    const int n = n0 + (t >> 3), c = t & 7;
    const uint2* y2v = reinterpret_cast<const uint2*>(yin);
    float4 av = gather16f(y2v, slot, rowptr[n], rowptr[n + 1], c);
    uint2 yv = y2v[(size_t)n0 * 8 + t];
    int b = t * 4;
    tl[b + 0] = fmaxf(blo(yv.x) + av.x + b1a[(b + 0) & 31], 0.f);
    tl[b + 1] = fmaxf(bhi(yv.x) + av.y + b1a[(b + 1) & 31], 0.f);
    tl[b + 2] = fmaxf(blo(yv.y) + av.z + b1a[(b + 2) & 31], 0.f);
    tl[b + 3] = fmaxf(bhi(yv.y) + av.w + b1a[(b + 3) & 31], 0.f);
  }
  __syncthreads();
  const int d = t & 31, ng = t >> 5;
  float acc[4];
  gemm32(tl, w1, d, ng, acc);
  float bias2 = b1b[d];
  float sc = bng[d] / sqrtf(bnv[d] + 1e-5f);
  float sh = bnb[d] - bnm[d] * sc;
#pragma unroll
  for (int j = 0; j < 4; ++j)
    hl[(ng * 4 + j) * DM + d] = fmaxf(acc[j] + bias2, 0.f) * sc + sh;
  __syncthreads();
  gemm32(hl, w2, d, ng, acc);
  u16* yo = yout + (size_t)n0 * DM;
#pragma unroll
  for (int j = 0; j < 4; ++j)
    yo[(ng * 4 + j) * DM + d] = f2b(acc[j]);
}

// Fused conv2-tail + head: agg=gather(y bf16); conv2 MLP + bn2 + fc1 + fc2 + pool.
__global__ __launch_bounds__(256) void k_tail(
    const u16* __restrict__ y,
    const int* __restrict__ rowptr, const int* __restrict__ slot,
    const int* __restrict__ batch,
    const float* __restrict__ b2a, const float* __restrict__ w2b, const float* __restrict__ b2b,
    const float* __restrict__ bng, const float* __restrict__ bnb,
    const float* __restrict__ bnm, const float* __restrict__ bnv,
    const float* __restrict__ fc1w, const float* __restrict__ fc1b,
    const float* __restrict__ fc2w, const float* __restrict__ fc2b,
    float* __restrict__ pool) {
  __shared__ float tl[1024], hl[1024], wA[1024], wB[1024], wC[1024];
  const int t = threadIdx.x;
  const int n0 = blockIdx.x * 32;
  reinterpret_cast<float4*>(wA)[t] = reinterpret_cast<const float4*>(w2b)[t];
  reinterpret_cast<float4*>(wB)[t] = reinterpret_cast<const float4*>(fc1w)[t];
  reinterpret_cast<float4*>(wC)[t] = reinterpret_cast<const float4*>(fc2w)[t];
  {
    const int n = n0 + (t >> 3), c = t & 7;
    const uint2* y2v = reinterpret_cast<const uint2*>(y);
    float4 av = gather16f(y2v, slot, rowptr[n], rowptr[n + 1], c);
    uint2 yv = y2v[(size_t)n0 * 8 + t];
    int b = t * 4;
    tl[b + 0] = fmaxf(blo(yv.x) + av.x + b2a[(b + 0) & 31], 0.f);
    tl[b + 1] = fmaxf(bhi(yv.x) + av.y + b2a[(b + 1) & 31], 0.f);
    tl[b + 2] = fmaxf(blo(yv.y) + av.z + b2a[(b + 2) & 31], 0.f);
    tl[b + 3] = fmaxf(bhi(yv.y) + av.w + b2a[(b + 3) & 31], 0.f);
  }
  __syncthreads();
  const int d = t & 31, ng = t >> 5;
  float acc[4];
  gemm32(tl, wA, d, ng, acc);
  {
    float bias2 = b2b[d];
    float sc = bng[d] / sqrtf(bnv[d] + 1e-5f);
    float sh = bnb[d] - bnm[d] * sc;
#pragma unroll
    for (int j = 0; j < 4; ++j)
      hl[(ng * 4 + j) * DM + d] = fmaxf(acc[j] + bias2, 0.f) * sc + sh;
  }
  __syncthreads();
  gemm32(hl, wB, d, ng, acc);
  {
    float b1 = fc1b[d];
#pragma unroll
    for (int j = 0; j < 4; ++j)
      tl[(ng * 4 + j) * DM + d] = fmaxf(acc[j] + b1, 0.f);
  }
  __syncthreads();
  gemm32(tl, wC, d, ng, acc);
  float b2 = fc2b[d];
  float h0 = acc[0] + b2, h1 = acc[1] + b2, h2 = acc[2] + b2, h3 = acc[3] + b2;
  int nb = n0 + ng * 4;
  int g0 = batch[nb], g1 = batch[nb + 1], g2 = batch[nb + 2], g3 = batch[nb + 3];
  float s = h0; int gp = g0;
  if (g1 == gp) { s += h1; } else { atomicAdd(&pool[gp * DM + d], s); gp = g1; s = h1; }
  if (g2 == gp) { s += h2; } else { atomicAdd(&pool[gp * DM + d], s); gp = g2; s = h2; }
  if (g3 == gp) { s += h3; } else { atomicAdd(&pool[gp * DM + d], s); gp = g3; s = h3; }
  atomicAdd(&pool[gp * DM + d], s);
}

// out[g,c] = (pool[g,:]/max(cnt,1)) @ lin_w + lin_b ; counts via binary search. f32 out.
__global__ __launch_bounds__(256) void k_out(
    const float* __restrict__ pool, const int* __restrict__ batch,
    const float* __restrict__ lw, const float* __restrict__ lb,
    float* __restrict__ out) {
  int tid = blockIdx.x * 256 + threadIdx.x;
  int g = tid >> 4, c = tid & 15;
  if (g >= NGR || c >= NCL) return;
  auto lower = [&](int key) {
    int lo = 0, hi = NN;
    while (lo < hi) { int mid = (lo + hi) >> 1; if (batch[mid] < key) lo = mid + 1; else hi = mid; }
    return lo;
  };
  int lo = lower(g), hi = lower(g + 1);
  float inv = 1.f / fmaxf((float)(hi - lo), 1.f);
  float acc = 0.f;
#pragma unroll
  for (int dd = 0; dd < DM; ++dd) acc = fmaf(pool[g * DM + dd], lw[dd * NCL + c], acc);
  out[g * NCL + c] = acc * inv + lb[c];
}

extern "C" void kernel_launch(void* const* d_in, const int* in_sizes, int n_in,
                              void* d_out, int out_size, void* d_ws, size_t ws_size,
                              hipStream_t stream) {
  const float* x   = (const float*)d_in[0];
  const int* ei    = (const int*)d_in[1];
  const int* batch = (const int*)d_in[2];
  const float* w1a = (const float*)d_in[3];  const float* b1a = (const float*)d_in[4];
  const float* w1b = (const float*)d_in[5];  const float* b1b = (const float*)d_in[6];
  const float* bn1g = (const float*)d_in[7]; const float* bn1b = (const float*)d_in[8];
  const float* bn1m = (const float*)d_in[9]; const float* bn1v = (const float*)d_in[10];
  const float* w2a = (const float*)d_in[11]; const float* b2a = (const float*)d_in[12];
  const float* w2b = (const float*)d_in[13]; const float* b2b = (const float*)d_in[14];
  const float* bn2g = (const float*)d_in[15]; const float* bn2b = (const float*)d_in[16];
  const float* bn2m = (const float*)d_in[17]; const float* bn2v = (const float*)d_in[18];
  const float* fc1w = (const float*)d_in[19]; const float* fc1b = (const float*)d_in[20];
  const float* fc2w = (const float*)d_in[21]; const float* fc2b = (const float*)d_in[22];
  const float* linw = (const float*)d_in[23]; const float* linb = (const float*)d_in[24];
  float* out = (float*)d_out;

  // workspace layout (~42 MB)
  char* ws = (char*)d_ws;
  const size_t SZB = (size_t)NN * DM * 2;          // 6.4 MB (bf16 table)
  const size_t SZE = (size_t)NE * 4;               // 12.8 MB
  const size_t SZH = (size_t)NB * BK * 4;          // 612 KB
  u16* y1     = (u16*)(ws);
  u16* y2     = (u16*)(ws + SZB);
  int* slot   = (int*)(ws + 2 * SZB);
  int* binned = (int*)(ws + 2 * SZB + SZE);
  int* hmat   = (int*)(ws + 2 * SZB + 2 * SZE);    // [NB][BK]
  int* offT   = (int*)(ws + 2 * SZB + 2 * SZE + SZH); // [BK][NB]
  int* rowptr = (int*)(ws + 2 * SZB + 2 * SZE + 2 * SZH); // NN+1
  int* colsum = rowptr + (NN + 32);                // BK
  int* cbase  = colsum + 512;                      // BK+1
  float* pool = (float*)(cbase + 512);             // 128 KB

  // CSR build via bucket binning — zero global atomics (exact counting sort)
  k_bhist2<<<NB, 256, 0, stream>>>(ei, hmat);
  k_bscan2<<<BK, 256, 0, stream>>>(hmat, offT, colsum);
  k_bscan3<<<1, 512, 0, stream>>>(colsum, cbase, rowptr, pool);
  // fused: edge binning (bin blocks FIRST, co-resident)  ||  y1 = x@w1a (bf16)
  k_gemm_bin<<<NB + GEMM_BLOCKS, 256, 0, stream>>>(x, w1a, y1, ei, cbase, offT, binned);
  k_fill2<<<BK, 512, 0, stream>>>(binned, cbase, rowptr, slot);

  k_mid<<<NN / 32, 256, 0, stream>>>(y1, y2, rowptr, slot, b1a, w1b, b1b,
                                     bn1g, bn1b, bn1m, bn1v, w2a);
  k_tail<<<NN / 32, 256, 0, stream>>>(y2, rowptr, slot, batch, b2a, w2b, b2b,
                                      bn2g, bn2b, bn2m, bn2v,
                                      fc1w, fc1b, fc2w, fc2b, pool);
  k_out<<<(NGR * 16) / 256, 256, 0, stream>>>(pool, batch, linw, linb, out);
}

// Round 7
// 304.680 us; speedup vs baseline: 1.1571x; 1.0645x over previous
//
#include <hip/hip_runtime.h>
#include <hip/hip_bf16.h>

typedef unsigned short u16;
typedef unsigned int u32;

#define NN 100000
#define NE 3200000
#define NF 128
#define DM 32
#define NGR 1024
#define NCL 10

#define GEMM_BLOCKS (NN / 32)          // 3125
#define BW 256                         // nodes per bucket (dst >> 8)
#define BK 391                         // ceil(NN / BW)
#define NEB 4096                       // edges per bin block (halved: 2x scatter parallelism)
#define NB 782                         // bin blocks = ceil(NE / NEB)
#define LSLOT 9216                     // LDS slot staging in fill2 (mean 8192 + 11 sigma)
#define LCAP 1536                      // LDS slot staging in mid/tail (mean 1024 + 16 sigma)

__device__ __forceinline__ float blo(u32 u) { return __uint_as_float(u << 16); }
__device__ __forceinline__ float bhi(u32 u) { return __uint_as_float(u & 0xffff0000u); }
__device__ __forceinline__ u16 f2b(float f) {
  __hip_bfloat16 h = __float2bfloat16(f);
  return *reinterpret_cast<u16*>(&h);
}

// ---------------------------------------------------------------------------
// 32x32 GEMM from LDS: out[j] = sum_k src[(ng*4+j)*32+k] * w[k*32+d]
__device__ __forceinline__ void gemm32(const float* __restrict__ s, const float* __restrict__ w,
                                       int d, int ng, float acc[4]) {
  const float4* r0 = reinterpret_cast<const float4*>(s + (ng * 4 + 0) * DM);
  const float4* r1 = reinterpret_cast<const float4*>(s + (ng * 4 + 1) * DM);
  const float4* r2 = reinterpret_cast<const float4*>(s + (ng * 4 + 2) * DM);
  const float4* r3 = reinterpret_cast<const float4*>(s + (ng * 4 + 3) * DM);
  float a0 = 0.f, a1 = 0.f, a2 = 0.f, a3 = 0.f;
#pragma unroll
  for (int kk = 0; kk < 8; ++kk) {
    float4 x0 = r0[kk], x1 = r1[kk], x2 = r2[kk], x3 = r3[kk];
    float w0 = w[(kk * 4 + 0) * DM + d];
    float w1 = w[(kk * 4 + 1) * DM + d];
    float w2 = w[(kk * 4 + 2) * DM + d];
    float w3 = w[(kk * 4 + 3) * DM + d];
    a0 = fmaf(x0.x, w0, a0); a0 = fmaf(x0.y, w1, a0); a0 = fmaf(x0.z, w2, a0); a0 = fmaf(x0.w, w3, a0);
    a1 = fmaf(x1.x, w0, a1); a1 = fmaf(x1.y, w1, a1); a1 = fmaf(x1.z, w2, a1); a1 = fmaf(x1.w, w3, a1);
    a2 = fmaf(x2.x, w0, a2); a2 = fmaf(x2.y, w1, a2); a2 = fmaf(x2.z, w2, a2); a2 = fmaf(x2.w, w3, a2);
    a3 = fmaf(x3.x, w0, a3); a3 = fmaf(x3.y, w1, a3); a3 = fmaf(x3.z, w2, a3); a3 = fmaf(x3.w, w3, a3);
  }
  acc[0] = a0; acc[1] = a1; acc[2] = a2; acc[3] = a3;
}

// Per-node gather from a bf16 table (rows of 32 bf16 = 64B). 8 lanes per node,
// lane c loads uint2 (4 bf16) per neighbor. `sl` is normally an LDS-staged
// slot list (block's contiguous range pre-loaded) so the per-burst chain is
// ds_read -> global row loads: one global latency per burst, not two.
__device__ __forceinline__ float4 gather16f(const uint2* __restrict__ y2v,
                                            const int* sl,
                                            int beg, int end, int c) {
  float ax = 0.f, ay = 0.f, az = 0.f, aw = 0.f;
  int i = beg;
  for (; i + 16 <= end; i += 16) {
    int s[16];
#pragma unroll
    for (int j = 0; j < 16; ++j) s[j] = sl[i + j];
    __builtin_amdgcn_sched_barrier(0);
    uint2 vv[16];
#pragma unroll
    for (int j = 0; j < 16; ++j) vv[j] = y2v[(size_t)s[j] * 8 + c];
    __builtin_amdgcn_sched_barrier(0);
#pragma unroll
    for (int j = 0; j < 16; ++j) {
      ax += blo(vv[j].x); ay += bhi(vv[j].x); az += blo(vv[j].y); aw += bhi(vv[j].y);
    }
  }
  if (i + 8 <= end) {
    int s[8];
#pragma unroll
    for (int j = 0; j < 8; ++j) s[j] = sl[i + j];
    __builtin_amdgcn_sched_barrier(0);
    uint2 vv[8];
#pragma unroll
    for (int j = 0; j < 8; ++j) vv[j] = y2v[(size_t)s[j] * 8 + c];
    __builtin_amdgcn_sched_barrier(0);
#pragma unroll
    for (int j = 0; j < 8; ++j) {
      ax += blo(vv[j].x); ay += bhi(vv[j].x); az += blo(vv[j].y); aw += bhi(vv[j].y);
    }
    i += 8;
  }
  for (; i < end; ++i) {
    int s = sl[i];
    uint2 v = y2v[(size_t)s * 8 + c];
    ax += blo(v.x); ay += bhi(v.x); az += blo(v.y); aw += bhi(v.y);
  }
  return make_float4(ax, ay, az, aw);
}

// ---------------------------------------------------------------------------
// Per-binblock bucket histogram -> hmat[b][k] (coalesced row write).
__global__ __launch_bounds__(256) void k_bhist2(const int* __restrict__ ei,
                                                int* __restrict__ hmat) {
  __shared__ int h[BK];
  const int t = threadIdx.x, b = blockIdx.x;
  for (int i = t; i < BK; i += 256) h[i] = 0;
  __syncthreads();
  const int e0 = b * NEB;
#pragma unroll
  for (int k = 0; k < NEB / 256; ++k) {
    int e = e0 + k * 256 + t;
    if (e < NE) atomicAdd(&h[ei[NE + e] >> 8], 1);
  }
  __syncthreads();
  for (int i = t; i < BK; i += 256) hmat[(size_t)b * BK + i] = h[i];
}

// Column-k exclusive scan of hmat -> offT[k][b]; column total -> colsum[k].
__global__ __launch_bounds__(256) void k_bscan2(const int* __restrict__ hmat,
                                                int* __restrict__ offT,
                                                int* __restrict__ colsum) {
  __shared__ int v[NB];
  __shared__ int ts[256];
  const int t = threadIdx.x, k = blockIdx.x;
  for (int i = t; i < NB; i += 256) v[i] = hmat[(size_t)i * BK + k];
  __syncthreads();
  int loc[4]; int s = 0;
#pragma unroll
  for (int j = 0; j < 4; ++j) {
    int idx = t * 4 + j;
    loc[j] = (idx < NB) ? v[idx] : 0;
    s += loc[j];
  }
  ts[t] = s;
  __syncthreads();
  for (int off = 1; off < 256; off <<= 1) {
    int x = (t >= off) ? ts[t - off] : 0;
    __syncthreads();
    ts[t] += x;
    __syncthreads();
  }
  int run = ts[t] - s;   // exclusive across threads
#pragma unroll
  for (int j = 0; j < 4; ++j) {
    int idx = t * 4 + j;
    if (idx < NB) offT[(size_t)k * NB + idx] = run;
    run += loc[j];
  }
  if (t == 255) colsum[k] = run;
}

// Scan colsum -> cbase; rowptr[NN]=NE; zero pool (replaces memset dispatch).
__global__ __launch_bounds__(512) void k_bscan3(const int* __restrict__ colsum,
                                                int* __restrict__ cbase,
                                                int* __restrict__ rowptr,
                                                float* __restrict__ pool) {
  __shared__ int ps[512];
  const int t = threadIdx.x;
  int own = (t < BK) ? colsum[t] : 0;
  ps[t] = own;
  __syncthreads();
  for (int off = 1; off < 512; off <<= 1) {
    int x = (t >= off) ? ps[t - off] : 0;
    __syncthreads();
    ps[t] += x;
    __syncthreads();
  }
  if (t < BK) cbase[t] = ps[t] - own;
  if (t == 0) { cbase[BK] = NE; rowptr[NN] = NE; }
  float4 z = {0.f, 0.f, 0.f, 0.f};
  float4* p4 = reinterpret_cast<float4*>(pool);
  for (int i = t; i < NGR * DM / 4; i += 512) p4[i] = z;
}

// ---------------------------------------------------------------------------
// Fused dispatch: blocks [0, NB) bin edges (FIRST so all bin blocks are
// co-resident from t=0); blocks [NB, ..) do y1 = x @ w1a.
__global__ __launch_bounds__(256) void k_gemm_bin(
    const float* __restrict__ x, const float* __restrict__ w, u16* __restrict__ y,
    const int* __restrict__ ei, const int* __restrict__ cbase,
    const int* __restrict__ offT, int* __restrict__ binned) {
  __shared__ alignas(16) char smem[32768];
  const int t = threadIdx.x;
  if (blockIdx.x < NB) {
    int* lofs = (int*)smem;           // [BK]
    int* lcur = lofs + BK;            // [BK]
    const int bb = blockIdx.x;
    for (int i = t; i < BK; i += 256) {
      lofs[i] = cbase[i] + offT[(size_t)i * NB + bb];
      lcur[i] = 0;
    }
    __syncthreads();
    const int e0 = bb * NEB;
#pragma unroll
    for (int k = 0; k < NEB / 256; ++k) {
      int e = e0 + k * 256 + t;
      if (e < NE) {
        int s = ei[e], d = ei[NE + e];
        int bk = d >> 8;
        int l = atomicAdd(&lcur[bk], 1);
        binned[lofs[bk] + l] = (s << 8) | (d & 255);
      }
    }
    return;
  }
  // ---- in_gemm: y1 = x @ w1a (bf16 store) ----
  float* wl = (float*)smem;           // 16KB
  float* xl = wl + NF * DM;           // 16KB
  const int n0 = (blockIdx.x - NB) * 32;
  {
    const float4* wv = reinterpret_cast<const float4*>(w);
    float4* wld = reinterpret_cast<float4*>(wl);
    for (int i = t; i < NF * DM / 4; i += 256) wld[i] = wv[i];
    const float4* xv = reinterpret_cast<const float4*>(x + (size_t)n0 * NF);
    float4* xld = reinterpret_cast<float4*>(xl);
    for (int i = t; i < 32 * NF / 4; i += 256) xld[i] = xv[i];
  }
  __syncthreads();
  const int d = t & 31, ng = t >> 5;
  const float4* r0 = reinterpret_cast<const float4*>(&xl[(ng * 4 + 0) * NF]);
  const float4* r1 = reinterpret_cast<const float4*>(&xl[(ng * 4 + 1) * NF]);
  const float4* r2 = reinterpret_cast<const float4*>(&xl[(ng * 4 + 2) * NF]);
  const float4* r3 = reinterpret_cast<const float4*>(&xl[(ng * 4 + 3) * NF]);
  float a0 = 0.f, a1 = 0.f, a2 = 0.f, a3 = 0.f;
#pragma unroll 4
  for (int kk = 0; kk < NF / 4; ++kk) {
    float4 x0 = r0[kk], x1 = r1[kk], x2 = r2[kk], x3 = r3[kk];
    float w0 = wl[(kk * 4 + 0) * DM + d];
    float w1 = wl[(kk * 4 + 1) * DM + d];
    float w2 = wl[(kk * 4 + 2) * DM + d];
    float w3 = wl[(kk * 4 + 3) * DM + d];
    a0 = fmaf(x0.x, w0, a0); a0 = fmaf(x0.y, w1, a0); a0 = fmaf(x0.z, w2, a0); a0 = fmaf(x0.w, w3, a0);
    a1 = fmaf(x1.x, w0, a1); a1 = fmaf(x1.y, w1, a1); a1 = fmaf(x1.z, w2, a1); a1 = fmaf(x1.w, w3, a1);
    a2 = fmaf(x2.x, w0, a2); a2 = fmaf(x2.y, w1, a2); a2 = fmaf(x2.z, w2, a2); a2 = fmaf(x2.w, w3, a2);
    a3 = fmaf(x3.x, w0, a3); a3 = fmaf(x3.y, w1, a3); a3 = fmaf(x3.z, w2, a3); a3 = fmaf(x3.w, w3, a3);
  }
  u16* yo = y + (size_t)n0 * DM;
  yo[(ng * 4 + 0) * DM + d] = f2b(a0);
  yo[(ng * 4 + 1) * DM + d] = f2b(a1);
  yo[(ng * 4 + 2) * DM + d] = f2b(a2);
  yo[(ng * 4 + 3) * DM + d] = f2b(a3);
}

// ---------------------------------------------------------------------------
// Per-bucket CSR finalize (512 threads): deg/scan/cursor and slot staging in
// LDS, coalesced stream-out. Fallback to direct writes on (improbable) overflow.
__global__ __launch_bounds__(512) void k_fill2(const int* __restrict__ binned,
                                               const int* __restrict__ cbase,
                                               int* __restrict__ rowptr,
                                               int* __restrict__ slot) {
  __shared__ int deg[BW], cur[BW], ps[256];
  __shared__ int lslot[LSLOT];
  const int t = threadIdx.x, b = blockIdx.x;
  const int n0 = b * BW;
  const int e0 = cbase[b], e1 = cbase[b + 1];
  const int cnt = e1 - e0;
  if (t < BW) deg[t] = 0;
  __syncthreads();
  for (int j = e0 + t; j < e1; j += 512) atomicAdd(&deg[binned[j] & 255], 1);
  __syncthreads();
  int own = (t < 256) ? deg[t] : 0;
  if (t < 256) ps[t] = own;
  __syncthreads();
  for (int off = 1; off < 256; off <<= 1) {
    int v = (t < 256 && t >= off) ? ps[t - off] : 0;
    __syncthreads();
    if (t < 256) ps[t] += v;
    __syncthreads();
  }
  if (t < 256) {
    int ex = ps[t] - own;
    cur[t] = ex;
    if (n0 + t < NN) rowptr[n0 + t] = e0 + ex;
  }
  __syncthreads();
  if (cnt <= LSLOT) {
    for (int j = e0 + t; j < e1; j += 512) {
      int v = binned[j];
      int p = atomicAdd(&cur[v & 255], 1);
      lslot[p] = (int)(((u32)v) >> 8);
    }
    __syncthreads();
    for (int j = t; j < cnt; j += 512) slot[e0 + j] = lslot[j];
  } else {
    for (int j = e0 + t; j < e1; j += 512) {
      int v = binned[j];
      int p = atomicAdd(&cur[v & 255], 1);
      slot[e0 + p] = (int)(((u32)v) >> 8);
    }
  }
}

// ---------------------------------------------------------------------------
// Fused conv1-tail: slot range for the block's 32 nodes staged in LDS (it's a
// contiguous range of `slot`), then agg=gather(yin bf16); t=relu(yin+agg+b1a);
// h1=bn1(relu(t@w1b+b1b)); yout(bf16) <- h1@w2a.  yout != yin (gather race).
__global__ __launch_bounds__(256) void k_mid(
    const u16* __restrict__ yin, u16* __restrict__ yout,
    const int* __restrict__ rowptr, const int* __restrict__ slot,
    const float* __restrict__ b1a, const float* __restrict__ w1b, const float* __restrict__ b1b,
    const float* __restrict__ bng, const float* __restrict__ bnb,
    const float* __restrict__ bnm, const float* __restrict__ bnv,
    const float* __restrict__ w2a) {
  __shared__ float tl[1024], hl[1024], w1[1024], w2[1024];
  __shared__ int ls[LCAP];
  const int t = threadIdx.x;
  const int n0 = blockIdx.x * 32;
  reinterpret_cast<float4*>(w1)[t] = reinterpret_cast<const float4*>(w1b)[t];
  reinterpret_cast<float4*>(w2)[t] = reinterpret_cast<const float4*>(w2a)[t];
  const int e0 = rowptr[n0];
  const int cnt = rowptr[n0 + 32] - e0;
  {
    int lim = cnt < LCAP ? cnt : LCAP;
    for (int j = t; j < lim; j += 256) ls[j] = slot[e0 + j];
  }
  __syncthreads();
  {
    const int n = n0 + (t >> 3), c = t & 7;
    const uint2* y2v = reinterpret_cast<const uint2*>(yin);
    int beg = rowptr[n] - e0, end = rowptr[n + 1] - e0;
    float4 av = (cnt <= LCAP) ? gather16f(y2v, ls, beg, end, c)
                              : gather16f(y2v, slot + e0, beg, end, c);
    uint2 yv = y2v[(size_t)n0 * 8 + t];
    int b = t * 4;
    tl[b + 0] = fmaxf(blo(yv.x) + av.x + b1a[(b + 0) & 31], 0.f);
    tl[b + 1] = fmaxf(bhi(yv.x) + av.y + b1a[(b + 1) & 31], 0.f);
    tl[b + 2] = fmaxf(blo(yv.y) + av.z + b1a[(b + 2) & 31], 0.f);
    tl[b + 3] = fmaxf(bhi(yv.y) + av.w + b1a[(b + 3) & 31], 0.f);
  }
  __syncthreads();
  const int d = t & 31, ng = t >> 5;
  float acc[4];
  gemm32(tl, w1, d, ng, acc);
  float bias2 = b1b[d];
  float sc = bng[d] / sqrtf(bnv[d] + 1e-5f);
  float sh = bnb[d] - bnm[d] * sc;
#pragma unroll
  for (int j = 0; j < 4; ++j)
    hl[(ng * 4 + j) * DM + d] = fmaxf(acc[j] + bias2, 0.f) * sc + sh;
  __syncthreads();
  gemm32(hl, w2, d, ng, acc);
  u16* yo = yout + (size_t)n0 * DM;
#pragma unroll
  for (int j = 0; j < 4; ++j)
    yo[(ng * 4 + j) * DM + d] = f2b(acc[j]);
}

// Fused conv2-tail + head: LDS slot staging; agg=gather(y bf16); conv2 MLP +
// bn2 + fc1 + fc2 + pool.
__global__ __launch_bounds__(256) void k_tail(
    const u16* __restrict__ y,
    const int* __restrict__ rowptr, const int* __restrict__ slot,
    const int* __restrict__ batch,
    const float* __restrict__ b2a, const float* __restrict__ w2b, const float* __restrict__ b2b,
    const float* __restrict__ bng, const float* __restrict__ bnb,
    const float* __restrict__ bnm, const float* __restrict__ bnv,
    const float* __restrict__ fc1w, const float* __restrict__ fc1b,
    const float* __restrict__ fc2w, const float* __restrict__ fc2b,
    float* __restrict__ pool) {
  __shared__ float tl[1024], hl[1024], wA[1024], wB[1024], wC[1024];
  __shared__ int ls[LCAP];
  const int t = threadIdx.x;
  const int n0 = blockIdx.x * 32;
  reinterpret_cast<float4*>(wA)[t] = reinterpret_cast<const float4*>(w2b)[t];
  reinterpret_cast<float4*>(wB)[t] = reinterpret_cast<const float4*>(fc1w)[t];
  reinterpret_cast<float4*>(wC)[t] = reinterpret_cast<const float4*>(fc2w)[t];
  const int e0 = rowptr[n0];
  const int cnt = rowptr[n0 + 32] - e0;
  {
    int lim = cnt < LCAP ? cnt : LCAP;
    for (int j = t; j < lim; j += 256) ls[j] = slot[e0 + j];
  }
  __syncthreads();
  {
    const int n = n0 + (t >> 3), c = t & 7;
    const uint2* y2v = reinterpret_cast<const uint2*>(y);
    int beg = rowptr[n] - e0, end = rowptr[n + 1] - e0;
    float4 av = (cnt <= LCAP) ? gather16f(y2v, ls, beg, end, c)
                              : gather16f(y2v, slot + e0, beg, end, c);
    uint2 yv = y2v[(size_t)n0 * 8 + t];
    int b = t * 4;
    tl[b + 0] = fmaxf(blo(yv.x) + av.x + b2a[(b + 0) & 31], 0.f);
    tl[b + 1] = fmaxf(bhi(yv.x) + av.y + b2a[(b + 1) & 31], 0.f);
    tl[b + 2] = fmaxf(blo(yv.y) + av.z + b2a[(b + 2) & 31], 0.f);
    tl[b + 3] = fmaxf(bhi(yv.y) + av.w + b2a[(b + 3) & 31], 0.f);
  }
  __syncthreads();
  const int d = t & 31, ng = t >> 5;
  float acc[4];
  gemm32(tl, wA, d, ng, acc);
  {
    float bias2 = b2b[d];
    float sc = bng[d] / sqrtf(bnv[d] + 1e-5f);
    float sh = bnb[d] - bnm[d] * sc;
#pragma unroll
    for (int j = 0; j < 4; ++j)
      hl[(ng * 4 + j) * DM + d] = fmaxf(acc[j] + bias2, 0.f) * sc + sh;
  }
  __syncthreads();
  gemm32(hl, wB, d, ng, acc);
  {
    float b1 = fc1b[d];
#pragma unroll
    for (int j = 0; j < 4; ++j)
      tl[(ng * 4 + j) * DM + d] = fmaxf(acc[j] + b1, 0.f);
  }
  __syncthreads();
  gemm32(tl, wC, d, ng, acc);
  float b2 = fc2b[d];
  float h0 = acc[0] + b2, h1 = acc[1] + b2, h2 = acc[2] + b2, h3 = acc[3] + b2;
  int nb = n0 + ng * 4;
  int g0 = batch[nb], g1 = batch[nb + 1], g2 = batch[nb + 2], g3 = batch[nb + 3];
  float s = h0; int gp = g0;
  if (g1 == gp) { s += h1; } else { atomicAdd(&pool[gp * DM + d], s); gp = g1; s = h1; }
  if (g2 == gp) { s += h2; } else { atomicAdd(&pool[gp * DM + d], s); gp = g2; s = h2; }
  if (g3 == gp) { s += h3; } else { atomicAdd(&pool[gp * DM + d], s); gp = g3; s = h3; }
  atomicAdd(&pool[gp * DM + d], s);
}

// out[g,c] = (pool[g,:]/max(cnt,1)) @ lin_w + lin_b ; counts via binary search. f32 out.
__global__ __launch_bounds__(256) void k_out(
    const float* __restrict__ pool, const int* __restrict__ batch,
    const float* __restrict__ lw, const float* __restrict__ lb,
    float* __restrict__ out) {
  int tid = blockIdx.x * 256 + threadIdx.x;
  int g = tid >> 4, c = tid & 15;
  if (g >= NGR || c >= NCL) return;
  auto lower = [&](int key) {
    int lo = 0, hi = NN;
    while (lo < hi) { int mid = (lo + hi) >> 1; if (batch[mid] < key) lo = mid + 1; else hi = mid; }
    return lo;
  };
  int lo = lower(g), hi = lower(g + 1);
  float inv = 1.f / fmaxf((float)(hi - lo), 1.f);
  float acc = 0.f;
#pragma unroll
  for (int dd = 0; dd < DM; ++dd) acc = fmaf(pool[g * DM + dd], lw[dd * NCL + c], acc);
  out[g * NCL + c] = acc * inv + lb[c];
}

extern "C" void kernel_launch(void* const* d_in, const int* in_sizes, int n_in,
                              void* d_out, int out_size, void* d_ws, size_t ws_size,
                              hipStream_t stream) {
  const float* x   = (const float*)d_in[0];
  const int* ei    = (const int*)d_in[1];
  const int* batch = (const int*)d_in[2];
  const float* w1a = (const float*)d_in[3];  const float* b1a = (const float*)d_in[4];
  const float* w1b = (const float*)d_in[5];  const float* b1b = (const float*)d_in[6];
  const float* bn1g = (const float*)d_in[7]; const float* bn1b = (const float*)d_in[8];
  const float* bn1m = (const float*)d_in[9]; const float* bn1v = (const float*)d_in[10];
  const float* w2a = (const float*)d_in[11]; const float* b2a = (const float*)d_in[12];
  const float* w2b = (const float*)d_in[13]; const float* b2b = (const float*)d_in[14];
  const float* bn2g = (const float*)d_in[15]; const float* bn2b = (const float*)d_in[16];
  const float* bn2m = (const float*)d_in[17]; const float* bn2v = (const float*)d_in[18];
  const float* fc1w = (const float*)d_in[19]; const float* fc1b = (const float*)d_in[20];
  const float* fc2w = (const float*)d_in[21]; const float* fc2b = (const float*)d_in[22];
  const float* linw = (const float*)d_in[23]; const float* linb = (const float*)d_in[24];
  float* out = (float*)d_out;

  // workspace layout (~43 MB)
  char* ws = (char*)d_ws;
  const size_t SZB = (size_t)NN * DM * 2;          // 6.4 MB (bf16 table)
  const size_t SZE = (size_t)NE * 4;               // 12.8 MB
  const size_t SZH = ((size_t)NB * BK * 4 + 511) & ~511ull; // 1.224 MB (padded)
  u16* y1     = (u16*)(ws);
  u16* y2     = (u16*)(ws + SZB);
  int* slot   = (int*)(ws + 2 * SZB);
  int* binned = (int*)(ws + 2 * SZB + SZE);
  int* hmat   = (int*)(ws + 2 * SZB + 2 * SZE);    // [NB][BK]
  int* offT   = (int*)(ws + 2 * SZB + 2 * SZE + SZH); // [BK][NB]
  int* rowptr = (int*)(ws + 2 * SZB + 2 * SZE + 2 * SZH); // NN+1
  int* colsum = rowptr + (NN + 32);                // BK
  int* cbase  = colsum + 512;                      // BK+1
  float* pool = (float*)(cbase + 512);             // 128 KB

  // CSR build via bucket binning — zero global atomics (exact counting sort)
  k_bhist2<<<NB, 256, 0, stream>>>(ei, hmat);
  k_bscan2<<<BK, 256, 0, stream>>>(hmat, offT, colsum);
  k_bscan3<<<1, 512, 0, stream>>>(colsum, cbase, rowptr, pool);
  // fused: edge binning (bin blocks FIRST, co-resident)  ||  y1 = x@w1a (bf16)
  k_gemm_bin<<<NB + GEMM_BLOCKS, 256, 0, stream>>>(x, w1a, y1, ei, cbase, offT, binned);
  k_fill2<<<BK, 512, 0, stream>>>(binned, cbase, rowptr, slot);

  k_mid<<<NN / 32, 256, 0, stream>>>(y1, y2, rowptr, slot, b1a, w1b, b1b,
                                     bn1g, bn1b, bn1m, bn1v, w2a);
  k_tail<<<NN / 32, 256, 0, stream>>>(y2, rowptr, slot, batch, b2a, w2b, b2b,
                                      bn2g, bn2b, bn2m, bn2v,
                                      fc1w, fc1b, fc2w, fc2b, pool);
  k_out<<<(NGR * 16) / 256, 256, 0, stream>>>(pool, batch, linw, linb, out);
}